// Round 5
// baseline (218.929 us; speedup 1.0000x reference)
//
#include <hip/hip_runtime.h>
#include <cstdint>
#include <cstddef>

typedef unsigned long long ull;
typedef _Float16 f16x8 __attribute__((ext_vector_type(8)));
typedef float f32x4 __attribute__((ext_vector_type(4)));

#define N_ROWS 8192
#define SPAN   8187u   // n - k
#define MULT   1600u   // (2^32) % 8187
#define TAU_INV 10.0f
#define TOTAL_SAMP 163840u
#define INIT_KEY 0x7F800000FFFFFFFFull   // q=+inf, col=~0

// ---------------- threefry2x32 (JAX-compatible) ----------------
__device__ __forceinline__ void tf_round(unsigned &x0, unsigned &x1, int r) {
    x0 += x1; x1 = (x1 << r) | (x1 >> (32 - r)); x1 ^= x0;
}
__device__ __forceinline__ void threefry2x32(unsigned k0, unsigned k1,
                                             unsigned c0, unsigned c1,
                                             unsigned &o0, unsigned &o1) {
    unsigned ks2 = k0 ^ k1 ^ 0x1BD11BDAu;
    unsigned x0 = c0 + k0, x1 = c1 + k1;
    tf_round(x0, x1, 13); tf_round(x0, x1, 15); tf_round(x0, x1, 26); tf_round(x0, x1, 6);
    x0 += k1;  x1 += ks2 + 1u;
    tf_round(x0, x1, 17); tf_round(x0, x1, 29); tf_round(x0, x1, 16); tf_round(x0, x1, 24);
    x0 += ks2; x1 += k0 + 2u;
    tf_round(x0, x1, 13); tf_round(x0, x1, 15); tf_round(x0, x1, 26); tf_round(x0, x1, 6);
    x0 += k0;  x1 += k1 + 3u;
    tf_round(x0, x1, 17); tf_round(x0, x1, 29); tf_round(x0, x1, 16); tf_round(x0, x1, 24);
    x0 += k1;  x1 += ks2 + 4u;
    tf_round(x0, x1, 13); tf_round(x0, x1, 15); tf_round(x0, x1, 26); tf_round(x0, x1, 6);
    x0 += ks2; x1 += k0 + 5u;
    o0 = x0; o1 = x1;
}

// ---------------- async global->LDS (16B) ----------------
__device__ __forceinline__ void async16(void* lds, const void* g) {
    __builtin_amdgcn_global_load_lds((const __attribute__((address_space(1))) void*)g,
                                     (__attribute__((address_space(3))) void*)lds, 16, 0, 0);
}

// Stage 1KB chunk q (0..7) of a 64x64-f16 tile (row-major, 128 B/row), XOR-swizzled
// source chunk so LDS dest stays lane-linear. LDS slot (r,c) = global chunk c^(r&7).
__device__ __forceinline__ void stage_chunk(char* lds_tile, const char* gtile, int q, int lane) {
    int off16 = (q << 6) + lane;
    int r = off16 >> 3;
    int slot = off16 & 7;
    int csrc = slot ^ (r & 7);
    async16(lds_tile + (q << 10), gtile + r * 128 + (csrc << 4));
}

__device__ __forceinline__ f16x8 read_frag(const char* tile, int row, int c) {
    return *(const f16x8*)(tile + row * 128 + (((c ^ (row & 7)) << 4)));
}

__device__ __forceinline__ void insert5(ull* a, ull kk) {
    bool l3 = kk < a[3], l2 = kk < a[2], l1 = kk < a[1], l0 = kk < a[0];
    a[4] = l3 ? a[3] : kk;
    a[3] = l3 ? (l2 ? a[2] : kk) : a[3];
    a[2] = l2 ? (l1 ? a[1] : kk) : a[2];
    a[1] = l1 ? (l0 ? a[0] : kk) : a[1];
    a[0] = l0 ? kk : a[0];
}

__device__ __forceinline__ float wave_maxf(float v) {
#pragma unroll
    for (int o = 32; o; o >>= 1) v = fmaxf(v, __shfl_xor(v, o));
    return v;
}
__device__ __forceinline__ float wave_sumf(float v) {
#pragma unroll
    for (int o = 32; o; o >>= 1) v += __shfl_xor(v, o);
    return v;
}
__device__ __forceinline__ ull wave_minu64(ull v) {
#pragma unroll
    for (int o = 32; o; o >>= 1) {
        ull w = __shfl_xor(v, o);
        v = (w < v) ? w : v;
    }
    return v;
}

// ---------------- Kernel 1: norms + f16 hi/lo split ----------------
__global__ void prep_kernel(const float* __restrict__ X,
                            float2* __restrict__ nsiv,
                            char* __restrict__ Xhi,
                            char* __restrict__ Xlo) {
    int t = blockIdx.x * 256 + threadIdx.x;
    int row = t >> 3, c = t & 7;
    const float4* src = (const float4*)(X + (size_t)row * 64 + c * 8);
    float4 a = src[0], b = src[1];
    float v[8] = {a.x, a.y, a.z, a.w, b.x, b.y, b.z, b.w};
    float ss = 0.f;
#pragma unroll
    for (int j = 0; j < 8; ++j) ss = fmaf(v[j], v[j], ss);
    ss += __shfl_xor(ss, 1);
    ss += __shfl_xor(ss, 2);
    ss += __shfl_xor(ss, 4);
    f16x8 h, l;
#pragma unroll
    for (int j = 0; j < 8; ++j) {
        _Float16 hh = (_Float16)v[j];
        h[j] = hh;
        l[j] = (_Float16)(v[j] - (float)hh);
    }
    *(f16x8*)(Xhi + (size_t)row * 128 + c * 16) = h;
    *(f16x8*)(Xlo + (size_t)row * 128 + c * 16) = l;
    if (c == 0) nsiv[row] = make_float2(ss, 1.0f / (1.0f - fminf(ss, 1.0f)));
}

// ---------------- Kernel 2: MFMA gram + fused top-5 ----------------
// grid 512 = 128 row-tiles x 4 col-chunks (2048 cols). 4 waves; wave w owns rows r0+16w..+15.
// Column stats live in LDS (staged once) so the K-loop has NO global loads ->
// the only vmcnt drain is the barrier (covered by the co-resident block).
__global__ __launch_bounds__(256, 2) void gram_topk(
        const char* __restrict__ Xhi, const char* __restrict__ Xlo,
        const float2* __restrict__ nsiv, ull* __restrict__ part) {
    __shared__ __align__(16) char lds[65536];
    char* Ahi = lds;
    char* Alo = lds + 8192;
    char* cnL = lds + 49152;          // 2048 float2 = 16 KB
    ull* dmp = (ull*)lds;             // union, post-loop only

    const int t = threadIdx.x, lane = t & 63, wv = t >> 6;
    const int lx = lane & 15, lq = lane >> 4;
    const int r0 = (blockIdx.x >> 2) * 64;
    const int ch = blockIdx.x & 3;
    const int j0base = ch * 2048;

    // stage A (block-constant), B buf0 (tile 0), and the chunk's nsiv slice
    const char* gAhi = Xhi + (size_t)r0 * 128;
    const char* gAlo = Xlo + (size_t)r0 * 128;
    stage_chunk(Ahi, gAhi, 2 * wv, lane);
    stage_chunk(Ahi, gAhi, 2 * wv + 1, lane);
    stage_chunk(Alo, gAlo, 2 * wv, lane);
    stage_chunk(Alo, gAlo, 2 * wv + 1, lane);
    {
        char* b0 = lds + 16384;
        stage_chunk(b0,        Xhi + (size_t)j0base * 128, 2 * wv, lane);
        stage_chunk(b0,        Xhi + (size_t)j0base * 128, 2 * wv + 1, lane);
        stage_chunk(b0 + 8192, Xlo + (size_t)j0base * 128, 2 * wv, lane);
        stage_chunk(b0 + 8192, Xlo + (size_t)j0base * 128, 2 * wv + 1, lane);
        const char* gcn = (const char*)(nsiv + j0base);
#pragma unroll
        for (int i = 0; i < 4; ++i) {
            int c = wv * 4 + i;       // 16 chunks of 1 KB, lane-linear
            async16(cnL + c * 1024, gcn + c * 1024 + lane * 16);
        }
    }

    // per-lane row stats (C/D layout: row = lq*4 + reg)
    int grow[4]; float rns[4];
#pragma unroll
    for (int r = 0; r < 4; ++r) {
        grow[r] = r0 + wv * 16 + lq * 4 + r;
        rns[r] = nsiv[grow[r]].x;
    }

    ull t5[4][5];
    float thr[4];
#pragma unroll
    for (int r = 0; r < 4; ++r) {
        thr[r] = __builtin_inff();
#pragma unroll
        for (int s = 0; s < 5; ++s) t5[r][s] = INIT_KEY;
    }

    __syncthreads();   // A + B0 + cn staged (barrier drains vmcnt)

    f16x8 ahi[2], alo[2];
#pragma unroll
    for (int kc = 0; kc < 2; ++kc) {
        ahi[kc] = read_frag(Ahi, wv * 16 + lx, kc * 4 + lq);
        alo[kc] = read_frag(Alo, wv * 16 + lx, kc * 4 + lq);
    }

    for (int it = 0; it < 32; ++it) {
        const int j0 = j0base + it * 64;
        char* cur = lds + ((it & 1) ? 32768 : 16384);

        if (it + 1 < 32) {   // stage next tile; only the end-of-iter barrier waits on it
            char* nxt = lds + ((it & 1) ? 16384 : 32768);
            const char* gBh = Xhi + (size_t)(j0 + 64) * 128;
            const char* gBl = Xlo + (size_t)(j0 + 64) * 128;
            stage_chunk(nxt,        gBh, 2 * wv, lane);
            stage_chunk(nxt,        gBh, 2 * wv + 1, lane);
            stage_chunk(nxt + 8192, gBl, 2 * wv, lane);
            stage_chunk(nxt + 8192, gBl, 2 * wv + 1, lane);
        }

        // column stats from LDS (lgkmcnt domain -- no vmcnt interaction)
        float2 cn[4];
#pragma unroll
        for (int ct = 0; ct < 4; ++ct)
            cn[ct] = *(const float2*)(cnL + (size_t)(it * 64 + ct * 16 + lx) * 8);

        f32x4 acc[4];
#pragma unroll
        for (int ct = 0; ct < 4; ++ct) {
            f16x8 bh0 = read_frag(cur, ct * 16 + lx, lq);
            f16x8 bh1 = read_frag(cur, ct * 16 + lx, 4 + lq);
            f16x8 bl0 = read_frag(cur + 8192, ct * 16 + lx, lq);
            f16x8 bl1 = read_frag(cur + 8192, ct * 16 + lx, 4 + lq);
            f32x4 a = {0.f, 0.f, 0.f, 0.f};
            a = __builtin_amdgcn_mfma_f32_16x16x32_f16(ahi[0], bh0, a, 0, 0, 0);
            a = __builtin_amdgcn_mfma_f32_16x16x32_f16(ahi[1], bh1, a, 0, 0, 0);
            a = __builtin_amdgcn_mfma_f32_16x16x32_f16(ahi[0], bl0, a, 0, 0, 0);
            a = __builtin_amdgcn_mfma_f32_16x16x32_f16(ahi[1], bl1, a, 0, 0, 0);
            a = __builtin_amdgcn_mfma_f32_16x16x32_f16(alo[0], bh0, a, 0, 0, 0);
            a = __builtin_amdgcn_mfma_f32_16x16x32_f16(alo[1], bh1, a, 0, 0, 0);
            acc[ct] = a;
        }

        // selection with monotone proxy q = d2 * civ_j  (per-row iv_i dropped)
#pragma unroll
        for (int ct = 0; ct < 4; ++ct) {
            const float civ    = cn[ct].y;
            const float cnsciv = cn[ct].x * civ;
            const float m2civ  = -2.0f * civ;
            const int   gcol   = j0 + ct * 16 + lx;
#pragma unroll
            for (int r = 0; r < 4; ++r) {
                float base = fmaf(rns[r], civ, cnsciv);
                float q    = fmaf(acc[ct][r], m2civ, base);
                // q >= 0 and thr = float of t5[r][4]>>32, so (q < thr) => kk < t5[r][4]
                if (q < thr[r] && gcol != grow[r]) {
                    ull kk = ((ull)__float_as_uint(q) << 32) | (unsigned)gcol;
                    insert5(t5[r], kk);
                    thr[r] = __uint_as_float((unsigned)(t5[r][4] >> 32));
                }
            }
        }

        __syncthreads();   // all waves done with cur; next buffer fully staged
    }

    // dump per-lane top5 and merge to per-row chunk top5 (keys carry col; q is proxy)
#pragma unroll
    for (int r = 0; r < 4; ++r)
#pragma unroll
        for (int s = 0; s < 5; ++s)
            dmp[(size_t)(wv * 16 + lq * 4 + r) * 80 + lx * 5 + s] = t5[r][s];
    __syncthreads();

    if (t < 64) {
        ull* p = dmp + (size_t)t * 80;
        const size_t base = (size_t)(r0 + t) * 20 + (size_t)ch * 5;
#pragma unroll
        for (int s = 0; s < 5; ++s) {
            ull best = ~0ull; int bp = 0;
            for (int q = 0; q < 80; ++q) {
                ull v = p[q];
                if (v < best) { best = v; bp = q; }
            }
            p[bp] = ~0ull;
            part[base + s] = best;
        }
    }
}

// ---------------- Kernel 3: finalize, 4 rows/block (wave per row), shuffle-parallel ----------------
__global__ __launch_bounds__(256) void finalize_kernel(
        const float* __restrict__ X, const float2* __restrict__ nsiv,
        const ull* __restrict__ part, float* __restrict__ rowloss) {
    const int t = threadIdx.x, lane = t & 63, wv = t >> 6;
    const int row = blockIdx.x * 4 + wv;

    // merge chunk top-5s (20 keys) -> global top-5 via 5 wave-min passes
    ull key = (lane < 20) ? part[(size_t)row * 20 + lane] : ~0ull;
    ull b[5];
#pragma unroll
    for (int s = 0; s < 5; ++s) {
        ull m = wave_minu64(key);
        b[s] = m;
        if (key == m) key = ~0ull;   // cols unique across chunks -> unique min
    }

    int pcol[5], ids[5];
#pragma unroll
    for (int s = 0; s < 5; ++s) { pcol[s] = (int)(unsigned)(b[s] & 0xFFFFFFFFull); ids[s] = pcol[s]; }
    // sort excluded ids ascending (tiny; every lane duplicates)
    for (int i = 0; i < 4; ++i)
        for (int j = 0; j < 4 - i; ++j)
            if (ids[j] > ids[j + 1]) { int tmp = ids[j]; ids[j] = ids[j + 1]; ids[j + 1] = tmp; }

    // column for this lane: lanes 0..19 = sampled negatives, 20..24 = positives
    int col = row;
    if (lane < 20) {
        unsigned m0 = (unsigned)(row * 20 + lane);
        unsigned hi, lo;
        threefry2x32(0u, 42u, m0, m0 + TOTAL_SAMP, hi, lo);
        unsigned samp = ((hi % SPAN) * MULT + (lo % SPAN)) % SPAN;
        int c = (int)samp;
#pragma unroll
        for (int s = 0; s < 5; ++s) c += (ids[s] <= c) ? 1 : 0;
        col = c;
    } else if (lane < 25) {
        col = pcol[lane - 20];
    }

    // exact fp32 Poincare distance term  -dist/tau  (diagonal -> -inf)
    float term = -INFINITY;
    if (lane < 25 && col != row) {
        const float4* xr = (const float4*)(X + (size_t)row * 64);
        const float4* xc = (const float4*)(X + (size_t)col * 64);
        float dot = 0.f;
#pragma unroll
        for (int k = 0; k < 16; ++k) {
            float4 a = xr[k];
            float4 c = xc[k];
            dot = fmaf(a.x, c.x, dot);
            dot = fmaf(a.y, c.y, dot);
            dot = fmaf(a.z, c.z, dot);
            dot = fmaf(a.w, c.w, dot);
        }
        float nsi = nsiv[row].x, nsj = nsiv[col].x;
        float d2  = fmaxf(nsi + nsj - 2.f * dot, 0.f);
        float ci  = 1.f - fminf(nsi, 1.f);
        float cj  = 1.f - fminf(nsj, 1.f);
        float den = fmaxf(ci * cj, 1e-9f);
        float z   = fmaxf(1.f + 2.f * d2 / den, 1.f);
        term = -acoshf(z) * TAU_INV;
    }

    // two masked LSEs across the wave
    float negt = (lane < 20) ? term : -INFINITY;
    float post = (lane >= 20 && lane < 25) ? term : -INFINITY;

    float nm = wave_maxf(negt);
    float ne = (lane < 20 && negt != -INFINITY) ? expf(negt - nm) : 0.f;
    float neg = nm + logf(wave_sumf(ne));

    float pm = wave_maxf(post);
    float pe = (lane >= 20 && lane < 25) ? expf(post - pm) : 0.f;
    float pos = pm + logf(wave_sumf(pe));

    if (lane == 0) rowloss[row] = neg - pos;
}

// ---------------- Kernel 4: deterministic tree sum ----------------
__global__ void reduce_kernel(const float* __restrict__ rl, float* __restrict__ out) {
    const int t = threadIdx.x;
    float s = 0.f;
#pragma unroll
    for (int i = 0; i < 32; ++i) s += rl[t + 256 * i];
#pragma unroll
    for (int o = 32; o; o >>= 1) s += __shfl_xor(s, o);
    __shared__ float ws4[4];
    if ((t & 63) == 0) ws4[t >> 6] = s;
    __syncthreads();
    if (t == 0) out[0] = (ws4[0] + ws4[1] + ws4[2] + ws4[3]) * (1.0f / 8192.0f);
}

// ---------------- launch ----------------
extern "C" void kernel_launch(void* const* d_in, const int* in_sizes, int n_in,
                              void* d_out, int out_size, void* d_ws, size_t ws_size,
                              hipStream_t stream) {
    (void)in_sizes; (void)n_in; (void)out_size; (void)ws_size;
    const float* X = (const float*)d_in[0];
    float* out = (float*)d_out;

    float2* nsiv    = (float2*)d_ws;                                  // 64 KB
    char*   Xhi     = (char*)d_ws + 65536;                            // 1 MB
    char*   Xlo     = (char*)d_ws + 65536 + 1048576;                  // 1 MB
    ull*    part    = (ull*)((char*)d_ws + 65536 + 2097152);          // 1.25 MB
    float*  rowloss = (float*)((char*)d_ws + 65536 + 2097152 + 1310720); // 32 KB

    prep_kernel<<<256, 256, 0, stream>>>(X, nsiv, Xhi, Xlo);
    gram_topk<<<512, 256, 0, stream>>>(Xhi, Xlo, nsiv, part);
    finalize_kernel<<<2048, 256, 0, stream>>>(X, nsiv, part, rowloss);
    reduce_kernel<<<1, 256, 0, stream>>>(rowloss, out);
}